// Round 8
// baseline (828.837 us; speedup 1.0000x reference)
//
#include <hip/hip_runtime.h>
#include <stdint.h>

typedef short bf16x8 __attribute__((ext_vector_type(8)));
typedef float f32x4 __attribute__((ext_vector_type(4)));

#define BATCH 8192
#define EMBED 8192
#define U0    1024
#define U1    256
#define NHEAD 6

// ---------- helpers ----------
__device__ __forceinline__ unsigned short f2bf(float f) {
  union { float f; unsigned int u; } v; v.f = f;
  unsigned int u = v.u;
  unsigned int r = u + 0x7FFFu + ((u >> 16) & 1u);  // RNE
  return (unsigned short)(r >> 16);
}
__device__ __forceinline__ unsigned int pk2(float lo, float hi) {
  return (unsigned int)f2bf(lo) | ((unsigned int)f2bf(hi) << 16);
}
__device__ __forceinline__ void async_copy16(const void* g, void* l) {
  __builtin_amdgcn_global_load_lds((const __attribute__((address_space(1))) void*)g,
                                   (__attribute__((address_space(3))) void*)l, 16, 0, 0);
}

// ---------- kernel 1: x fp32 -> bf16 (grid-stride, 2048 blocks per G11) ----------
__global__ void cvt_x_kernel(const float* __restrict__ x, unsigned short* __restrict__ xb) {
  const long total = (long)BATCH * EMBED;
  const long stride = (long)gridDim.x * blockDim.x * 8;
  for (long i = ((long)blockIdx.x * blockDim.x + threadIdx.x) * 8; i < total; i += stride) {
    float4 a = *(const float4*)(x + i);
    float4 b = *(const float4*)(x + i + 4);
    uint4 r;
    r.x = pk2(a.x, a.y); r.y = pk2(a.z, a.w);
    r.z = pk2(b.x, b.y); r.w = pk2(b.z, b.w);
    *(uint4*)(xb + i) = r;
  }
}

// ---------- kernel 2: transpose + convert: in[R][C] fp32 -> out[C][R] bf16 ----------
__global__ void transpose_cvt_kernel(const float* __restrict__ in, unsigned short* __restrict__ out,
                                     int R, int C, long in_z, long out_z) {
  __shared__ unsigned short tile[64][65];
  const float* inp = in + (long)blockIdx.z * in_z;
  unsigned short* outp = out + (long)blockIdx.z * out_z;
  int r0 = blockIdx.x * 64;
  int c0 = blockIdx.y * 64;
  int lc = threadIdx.x & 63;
  int lr = threadIdx.x >> 6;  // 0..3
#pragma unroll
  for (int i = 0; i < 16; i++) {
    int r = lr + i * 4;
    tile[r][lc] = f2bf(inp[(long)(r0 + r) * C + (c0 + lc)]);
  }
  __syncthreads();
#pragma unroll
  for (int i = 0; i < 16; i++) {
    int c = lr + i * 4;
    outp[(long)(c0 + c) * R + (r0 + lc)] = tile[lc][c];
  }
}

// ---------- kernel 3: bucket rows by command (single block, ballot-aggregated) ----------
__global__ void bucket_kernel(const int* __restrict__ cmd, int* __restrict__ idxlist,
                              int* __restrict__ meta) {
  __shared__ int cnt[NHEAD], cur[NHEAD], off[NHEAD + 1];
  int tid = threadIdx.x;            // 1024 threads = 16 waves
  int lane = tid & 63, wave = tid >> 6;
  if (tid < NHEAD) cnt[tid] = 0;
  __syncthreads();
  for (int base = wave * 64; base < BATCH; base += 1024) {
    int c = cmd[base + lane];
#pragma unroll
    for (int h2 = 0; h2 < NHEAD; h2++) {
      unsigned long long m = __ballot(c == h2);
      if (lane == 0 && m) atomicAdd(&cnt[h2], __popcll(m));
    }
  }
  __syncthreads();
  if (tid == 0) {
    int s = 0;
    for (int h2 = 0; h2 < NHEAD; h2++) { off[h2] = s; s += cnt[h2]; }
    off[NHEAD] = s;
  }
  __syncthreads();
  if (tid < NHEAD) cur[tid] = off[tid];
  if (tid <= NHEAD) meta[tid] = off[tid];
  __syncthreads();
  for (int base = wave * 64; base < BATCH; base += 1024) {
    int b = base + lane;
    int c = cmd[b];
    int pos = 0;
#pragma unroll
    for (int h2 = 0; h2 < NHEAD; h2++) {
      unsigned long long m = __ballot(c == h2);
      if (m) {
        int leader = (int)(__ffsll((unsigned long long)m) - 1);
        int wbase = 0;
        if (lane == leader) wbase = atomicAdd(&cur[h2], __popcll(m));
        wbase = __shfl(wbase, leader);
        if (c == h2) pos = wbase + __popcll(m & ((1ULL << lane) - 1ULL));
      }
    }
    idxlist[pos] = b;
  }
}

// ---------- kernel 4: GEMM split-K=2 (m97-exact 4-wave structure) ----------
// A = xb[8192][8192] bf16; B = wt[1024][8192] bf16 (fc_W^T).
// 128x128 tile, BK=64, 4 waves 2x2, wave 64x64 (4x4 of 16x16x32 MFMA).
// Grid 1024 = 8 xcd x 8 by x 2 kh x 8 bx (bijective swizzle): per XCD 8 A-panels,
// bx fastest so panel-sharing blocks are co-temporal on one XCD's L2.
// 1024 blocks -> 3-4 blocks/CU = 3-4 independent barrier groups (m103 operating point).
// Output: bf16 partials pb[kh][8192][1024] (fp32 accum, rounded once per half).
__global__ __launch_bounds__(256) void gemm_kernel(const unsigned short* __restrict__ xb,
                                                   const unsigned short* __restrict__ wt,
                                                   unsigned short* __restrict__ pbuf) {
  __shared__ uint4 As[1024];  // 16 KB
  __shared__ uint4 Bs[1024];  // 16 KB
  int tid  = threadIdx.x;
  int lane = tid & 63;
  int wave = tid >> 6;
  int wm = wave >> 1, wn = wave & 1;

  int f = blockIdx.x;         // 0..1023
  int xcd = f & 7;
  int g = f >> 3;             // 0..127
  int by = xcd * 8 + (g >> 4);
  int rem = g & 15;
  int kh = rem >> 3;          // 0..1
  int bx = rem & 7;
  int m0 = by * 128;
  int n0 = bx * 128;
  int l15 = lane & 15, lq = lane >> 4;

  // staging sources: combo c = (cwm*2+cks)*4+cmi ; this wave handles c = wave*4..wave*4+3
  long asrc[4], bsrc[4];
#pragma unroll
  for (int j = 0; j < 4; j++) {
    int c = wave * 4 + j;
    int cwm = c >> 3, cks = (c >> 2) & 1, cmi = c & 3;
    int kofs = cks * 32 + lq * 8;
    asrc[j] = (long)(m0 + cwm * 64 + cmi * 16 + l15) * EMBED + kofs;
    bsrc[j] = (long)(n0 + cwm * 64 + cmi * 16 + l15) * EMBED + kofs;
  }

  f32x4 zero = {0.f, 0.f, 0.f, 0.f};
  f32x4 acc[4][4];
#pragma unroll
  for (int mi = 0; mi < 4; mi++)
#pragma unroll
    for (int ni = 0; ni < 4; ni++) acc[mi][ni] = zero;

  const int kbeg = kh * 4096;
  for (int k0 = kbeg; k0 < kbeg + 4096; k0 += 64) {
    __syncthreads();
#pragma unroll
    for (int j = 0; j < 4; j++) {
      int c = wave * 4 + j;
      async_copy16(xb + asrc[j] + k0, &As[c * 64 + lane]);
      async_copy16(wt + bsrc[j] + k0, &Bs[c * 64 + lane]);
    }
    __syncthreads();
#pragma unroll
    for (int ks = 0; ks < 2; ks++) {
      bf16x8 af[4], bfr[4];
#pragma unroll
      for (int mi = 0; mi < 4; mi++) af[mi] = *(const bf16x8*)&As[((wm * 2 + ks) * 4 + mi) * 64 + lane];
#pragma unroll
      for (int ni = 0; ni < 4; ni++) bfr[ni] = *(const bf16x8*)&Bs[((wn * 2 + ks) * 4 + ni) * 64 + lane];
#pragma unroll
      for (int mi = 0; mi < 4; mi++)
#pragma unroll
        for (int ni = 0; ni < 4; ni++)
          acc[mi][ni] = __builtin_amdgcn_mfma_f32_16x16x32_bf16(af[mi], bfr[ni], acc[mi][ni], 0, 0, 0);
    }
  }

  // store bf16 partials.  D: col=lane&15, row=(lane>>4)*4+reg
  unsigned short* p = pbuf + (long)kh * (8192L * 1024);
#pragma unroll
  for (int ni = 0; ni < 4; ni++) {
    int col = n0 + wn * 64 + ni * 16 + l15;
#pragma unroll
    for (int mi = 0; mi < 4; mi++) {
      int rbase = m0 + wm * 64 + mi * 16 + lq * 4;
#pragma unroll
      for (int r = 0; r < 4; r++) {
        p[(long)(rbase + r) * U0 + col] = f2bf(acc[mi][ni][r]);
      }
    }
  }
}

// ---------- kernel 5: reduce partials + bias + relu -> h bf16 (in place over pb0) ----------
// h aliases pb[0]: thread i reads its own 16B of pb0 and writes the same 16B. No
// cross-thread overlap -> safe in-place.
__global__ __launch_bounds__(256) void reduce_kernel(unsigned short* __restrict__ pb,
                                                     const float* __restrict__ fc_b) {
  long i = ((long)blockIdx.x * 256 + threadIdx.x) * 8;
  const unsigned short* p1 = pb + 8192L * 1024;
  uint4 a = *(const uint4*)(pb + i);
  uint4 b = *(const uint4*)(p1 + i);
  int cb = (int)(i & (U0 - 1));
  float4 b0 = *(const float4*)(fc_b + cb);
  float4 b1 = *(const float4*)(fc_b + cb + 4);
  const unsigned int* aw = (const unsigned int*)&a;
  const unsigned int* bw = (const unsigned int*)&b;
  float bias[8] = {b0.x, b0.y, b0.z, b0.w, b1.x, b1.y, b1.z, b1.w};
  uint4 r;
  unsigned int* rw = (unsigned int*)&r;
#pragma unroll
  for (int j = 0; j < 4; j++) {
    union { unsigned int u; float f; } lo0, hi0, lo1, hi1;
    lo0.u = (aw[j] & 0xFFFFu) << 16; hi0.u = aw[j] & 0xFFFF0000u;
    lo1.u = (bw[j] & 0xFFFFu) << 16; hi1.u = bw[j] & 0xFFFF0000u;
    float vlo = lo0.f + lo1.f + bias[2 * j];
    float vhi = hi0.f + hi1.f + bias[2 * j + 1];
    vlo = vlo > 0.f ? vlo : 0.f;
    vhi = vhi > 0.f ? vhi : 0.f;
    rw[j] = pk2(vlo, vhi);
  }
  *(uint4*)(pb + i) = r;
}

// ---------- kernel 6: selected-head MLP + epilogue ----------
__global__ __launch_bounds__(256) void head_kernel(const unsigned short* __restrict__ h,
                                                   const unsigned short* __restrict__ w1t,
                                                   const float* __restrict__ W1,
                                                   const float* __restrict__ b1,
                                                   const float* __restrict__ W2,
                                                   const float* __restrict__ b2,
                                                   const float* __restrict__ ego,
                                                   const int* __restrict__ idxlist,
                                                   const int* __restrict__ meta,
                                                   float* __restrict__ out) {
  int hd = blockIdx.y;
  int off = meta[hd];
  int cnt = meta[hd + 1] - off;
  int t0 = blockIdx.x * 32;
  if (t0 >= cnt) return;

  __shared__ int ridx[32];
  __shared__ float h1s[32][257];
  __shared__ float w2s[1024];  // W2[hd] preloaded: [256][4]
  int tid = threadIdx.x;
  if (tid < 32) {
    int i = t0 + tid;
    ridx[tid] = idxlist[off + (i < cnt ? i : 0)];
  }
  *(float4*)&w2s[tid * 4] = *(const float4*)(W2 + (long)hd * 1024 + tid * 4);
  __syncthreads();

  int lane = tid & 63, wave = tid >> 6;
  int l15 = lane & 15, lq = lane >> 4;

  long abase[2];
#pragma unroll
  for (int mi = 0; mi < 2; mi++) abase[mi] = (long)ridx[mi * 16 + l15] * U0 + lq * 8;
  long bbase[4];
#pragma unroll
  for (int ni = 0; ni < 4; ni++)
    bbase[ni] = (long)(hd * 256 + wave * 64 + ni * 16 + l15) * 1024 + lq * 8;

  f32x4 zero = {0.f, 0.f, 0.f, 0.f};
  f32x4 acc[2][4];
#pragma unroll
  for (int mi = 0; mi < 2; mi++)
#pragma unroll
    for (int ni = 0; ni < 4; ni++) acc[mi][ni] = zero;

#pragma unroll 2
  for (int k0 = 0; k0 < 1024; k0 += 32) {
    bf16x8 af[2], bfr[4];
#pragma unroll
    for (int mi = 0; mi < 2; mi++) af[mi] = *(const bf16x8*)(h + abase[mi] + k0);
#pragma unroll
    for (int ni = 0; ni < 4; ni++) bfr[ni] = *(const bf16x8*)(w1t + bbase[ni] + k0);
#pragma unroll
    for (int mi = 0; mi < 2; mi++)
#pragma unroll
      for (int ni = 0; ni < 4; ni++)
        acc[mi][ni] = __builtin_amdgcn_mfma_f32_16x16x32_bf16(af[mi], bfr[ni], acc[mi][ni], 0, 0, 0);
  }

  // ego contribution (fp32 exact) + bias + relu -> LDS
  const float* W1e = W1 + (long)hd * 1027 * 256 + (long)1024 * 256;  // rows 1024..1026
#pragma unroll
  for (int mi = 0; mi < 2; mi++)
#pragma unroll
    for (int r = 0; r < 4; r++) {
      int rl = mi * 16 + lq * 4 + r;
      int b = ridx[rl];
      float e0 = ego[b * 3 + 0], e1 = ego[b * 3 + 1], e2 = ego[b * 3 + 2];
#pragma unroll
      for (int ni = 0; ni < 4; ni++) {
        int col = wave * 64 + ni * 16 + l15;
        float v = acc[mi][ni][r] + b1[hd * 256 + col]
                + e0 * W1e[col] + e1 * W1e[256 + col] + e2 * W1e[512 + col];
        h1s[rl][col] = v > 0.f ? v : 0.f;
      }
    }
  __syncthreads();

  // h2 = h1 @ W2[hd] + b2[hd]; tanh/softplus epilogue; scatter by original row
  if (tid < 128) {
    int t = tid >> 2, o2 = tid & 3;
    if (t0 + t < cnt) {
      float s0 = 0.f, s1 = 0.f, s2 = 0.f, s3 = 0.f;
#pragma unroll 4
      for (int i = 0; i < 256; i += 4) {
        s0 += h1s[t][i + 0] * w2s[(i + 0) * 4 + o2];
        s1 += h1s[t][i + 1] * w2s[(i + 1) * 4 + o2];
        s2 += h1s[t][i + 2] * w2s[(i + 2) * 4 + o2];
        s3 += h1s[t][i + 3] * w2s[(i + 3) * 4 + o2];
      }
      float sum = b2[hd * 4 + o2] + ((s0 + s1) + (s2 + s3));
      int b = ridx[t];
      float res;
      if (o2 < 2) {
        res = 5.0f * tanhf(sum * 0.2f);
      } else {
        float z = sum + 4.99323838f;  // log(exp(5)-1)
        res = (z > 20.f ? z : log1pf(expf(z))) + 1e-4f;
      }
      out[b * 4 + o2] = res;
    }
  }
}

// ---------- launcher ----------
extern "C" void kernel_launch(void* const* d_in, const int* in_sizes, int n_in,
                              void* d_out, int out_size, void* d_ws, size_t ws_size,
                              hipStream_t stream) {
  const float* x   = (const float*)d_in[0];
  const int*   cmd = (const int*)d_in[1];
  const float* ego = (const float*)d_in[2];
  const float* fcW = (const float*)d_in[3];
  const float* fcb = (const float*)d_in[4];
  const float* W1  = (const float*)d_in[5];
  const float* b1  = (const float*)d_in[6];
  const float* W2  = (const float*)d_in[7];
  const float* b2  = (const float*)d_in[8];
  float* out = (float*)d_out;

  char* ws = (char*)d_ws;
  unsigned short* xb   = (unsigned short*)(ws);                 // 128 MB  x bf16
  unsigned short* wt   = (unsigned short*)(ws + 134217728);     // 16 MB   fc_W^T bf16
  unsigned short* pbuf = (unsigned short*)(ws + 150994944);     // 32 MB   partials [2][8192][1024]; pb0 becomes h
  unsigned short* hbuf = pbuf;                                  // h aliases pb0 (reduce is in-place)
  unsigned short* w1t  = (unsigned short*)(ws + 184549376);     // 3 MB    W1^T bf16
  int* idxlist         = (int*)(ws + 187695104);                // 32 KB
  int* meta            = (int*)(ws + 187727872);                // 7 ints

  hipLaunchKernelGGL(cvt_x_kernel, dim3(2048), dim3(256), 0, stream, x, xb);
  hipLaunchKernelGGL(transpose_cvt_kernel, dim3(128, 16, 1), dim3(256), 0, stream,
                     fcW, wt, 8192, 1024, 0L, 0L);
  hipLaunchKernelGGL(transpose_cvt_kernel, dim3(16, 4, 6), dim3(256), 0, stream,
                     W1, w1t, 1024, 256, (long)1027 * 256, (long)256 * 1024);
  hipLaunchKernelGGL(bucket_kernel, dim3(1), dim3(1024), 0, stream, cmd, idxlist, meta);
  hipLaunchKernelGGL(gemm_kernel, dim3(1024), dim3(256), 0, stream, xb, wt, pbuf);
  hipLaunchKernelGGL(reduce_kernel, dim3(4096), dim3(256), 0, stream, pbuf, fcb);
  hipLaunchKernelGGL(head_kernel, dim3(256, 6), dim3(256), 0, stream,
                     hbuf, w1t, W1, b1, W2, b2, ego, idxlist, meta, out);
}

// Round 9
// 777.527 us; speedup vs baseline: 1.0660x; 1.0660x over previous
//
#include <hip/hip_runtime.h>
#include <stdint.h>

typedef short bf16x8 __attribute__((ext_vector_type(8)));
typedef float f32x4 __attribute__((ext_vector_type(4)));

#define BATCH 8192
#define EMBED 8192
#define U0    1024
#define U1    256
#define NHEAD 6

// ---------- helpers ----------
__device__ __forceinline__ unsigned short f2bf(float f) {
  union { float f; unsigned int u; } v; v.f = f;
  unsigned int u = v.u;
  unsigned int r = u + 0x7FFFu + ((u >> 16) & 1u);  // RNE
  return (unsigned short)(r >> 16);
}
__device__ __forceinline__ unsigned int pk2(float lo, float hi) {
  return (unsigned int)f2bf(lo) | ((unsigned int)f2bf(hi) << 16);
}
__device__ __forceinline__ void async_copy16(const void* g, void* l) {
  __builtin_amdgcn_global_load_lds((const __attribute__((address_space(1))) void*)g,
                                   (__attribute__((address_space(3))) void*)l, 16, 0, 0);
}

// ---------- kernel 1: x fp32 -> bf16 (grid-stride, 2048 blocks per G11) ----------
__global__ void cvt_x_kernel(const float* __restrict__ x, unsigned short* __restrict__ xb) {
  const long total = (long)BATCH * EMBED;
  const long stride = (long)gridDim.x * blockDim.x * 8;
  for (long i = ((long)blockIdx.x * blockDim.x + threadIdx.x) * 8; i < total; i += stride) {
    float4 a = *(const float4*)(x + i);
    float4 b = *(const float4*)(x + i + 4);
    uint4 r;
    r.x = pk2(a.x, a.y); r.y = pk2(a.z, a.w);
    r.z = pk2(b.x, b.y); r.w = pk2(b.z, b.w);
    *(uint4*)(xb + i) = r;
  }
}

// ---------- kernel 2: transpose + convert: in[R][C] fp32 -> out[C][R] bf16 ----------
__global__ void transpose_cvt_kernel(const float* __restrict__ in, unsigned short* __restrict__ out,
                                     int R, int C, long in_z, long out_z) {
  __shared__ unsigned short tile[64][65];
  const float* inp = in + (long)blockIdx.z * in_z;
  unsigned short* outp = out + (long)blockIdx.z * out_z;
  int r0 = blockIdx.x * 64;
  int c0 = blockIdx.y * 64;
  int lc = threadIdx.x & 63;
  int lr = threadIdx.x >> 6;  // 0..3
#pragma unroll
  for (int i = 0; i < 16; i++) {
    int r = lr + i * 4;
    tile[r][lc] = f2bf(inp[(long)(r0 + r) * C + (c0 + lc)]);
  }
  __syncthreads();
#pragma unroll
  for (int i = 0; i < 16; i++) {
    int c = lr + i * 4;
    outp[(long)(c0 + c) * R + (r0 + lc)] = tile[lc][c];
  }
}

// ---------- kernel 3: bucket rows by command (single block, ballot-aggregated) ----------
__global__ void bucket_kernel(const int* __restrict__ cmd, int* __restrict__ idxlist,
                              int* __restrict__ meta) {
  __shared__ int cnt[NHEAD], cur[NHEAD], off[NHEAD + 1];
  int tid = threadIdx.x;            // 1024 threads = 16 waves
  int lane = tid & 63, wave = tid >> 6;
  if (tid < NHEAD) cnt[tid] = 0;
  __syncthreads();
  for (int base = wave * 64; base < BATCH; base += 1024) {
    int c = cmd[base + lane];
#pragma unroll
    for (int h2 = 0; h2 < NHEAD; h2++) {
      unsigned long long m = __ballot(c == h2);
      if (lane == 0 && m) atomicAdd(&cnt[h2], __popcll(m));
    }
  }
  __syncthreads();
  if (tid == 0) {
    int s = 0;
    for (int h2 = 0; h2 < NHEAD; h2++) { off[h2] = s; s += cnt[h2]; }
    off[NHEAD] = s;
  }
  __syncthreads();
  if (tid < NHEAD) cur[tid] = off[tid];
  if (tid <= NHEAD) meta[tid] = off[tid];
  __syncthreads();
  for (int base = wave * 64; base < BATCH; base += 1024) {
    int b = base + lane;
    int c = cmd[b];
    int pos = 0;
#pragma unroll
    for (int h2 = 0; h2 < NHEAD; h2++) {
      unsigned long long m = __ballot(c == h2);
      if (m) {
        int leader = (int)(__ffsll((unsigned long long)m) - 1);
        int wbase = 0;
        if (lane == leader) wbase = atomicAdd(&cur[h2], __popcll(m));
        wbase = __shfl(wbase, leader);
        if (c == h2) pos = wbase + __popcll(m & ((1ULL << lane) - 1ULL));
      }
    }
    idxlist[pos] = b;
  }
}

// ---------- kernel 4: GEMM split-K=2, 8-wave 128x128 (R3-measured structure) ----------
// A = xb[8192][8192] bf16; B = wt[1024][8192] bf16 (fc_W^T).
// 128x128 tile, BK=64, 8 waves (512 thr) in 4x2, wave-tile 32x64 (2x4 of 16x16x32).
// Body identical to the R3-benchmarked kernel (256us / 535 TF, VGPR 44); only deltas:
// kh split (K halves), bf16 partial store. Resources: VGPR 44 <= 64 (8 waves/SIMD ok),
// LDS 32 KB x 4 blocks = 128 <= 160 KB -> 4 blocks/CU x 8 waves = 32 waves/CU max,
// 4 independent barrier groups (A/B test vs R3's 2 groups at same wave count).
// Grid 1024 = 8 xcd x 8 by x 2 kh x 8 bx bijective swizzle, bx fastest.
__global__ __launch_bounds__(512) void gemm_kernel(const unsigned short* __restrict__ xb,
                                                   const unsigned short* __restrict__ wt,
                                                   unsigned short* __restrict__ pbuf) {
  __shared__ uint4 As[1024];  // 16 KB: slot ((wm*2+ks)*2+mi)*64 + lane
  __shared__ uint4 Bs[1024];  // 16 KB: slot ((wn*2+ks)*4+ni)*64 + lane
  int tid  = threadIdx.x;
  int lane = tid & 63;
  int wave = tid >> 6;        // 0..7
  int wm = wave >> 1;         // 0..3
  int wn = wave & 1;          // 0..1

  int f = blockIdx.x;         // 0..1023
  int xcd = f & 7;
  int g = f >> 3;             // 0..127
  int by = xcd * 8 + (g >> 4);
  int rem = g & 15;
  int kh = rem >> 3;          // 0..1
  int bx = rem & 7;
  int m0 = by * 128;
  int n0 = bx * 128;
  int l15 = lane & 15, lq = lane >> 4;

  // staging: 2048 slots over 512 lanes = 2 A-copies + 2 B-copies per lane.
  long asrc[2], bsrc[2];
#pragma unroll
  for (int j = 0; j < 2; j++) {
    int ca = wave * 2 + j;                 // 0..15 = (cwm*2+cks)*2+cmi
    int cwm = ca >> 2, cka = (ca >> 1) & 1, cmi = ca & 1;
    asrc[j] = (long)(m0 + cwm * 32 + cmi * 16 + l15) * EMBED + cka * 32 + lq * 8;
    int cb = wave * 2 + j;                 // 0..15 = (cwn*2+cks)*4+cni
    int cwn = cb >> 3, ckb = (cb >> 2) & 1, cni = cb & 3;
    bsrc[j] = (long)(n0 + cwn * 64 + cni * 16 + l15) * EMBED + ckb * 32 + lq * 8;
  }

  f32x4 zero = {0.f, 0.f, 0.f, 0.f};
  f32x4 acc[2][4];
#pragma unroll
  for (int mi = 0; mi < 2; mi++)
#pragma unroll
    for (int ni = 0; ni < 4; ni++) acc[mi][ni] = zero;

  const int kbeg = kh * 4096;
  for (int k0 = kbeg; k0 < kbeg + 4096; k0 += 64) {
    __syncthreads();
#pragma unroll
    for (int j = 0; j < 2; j++) {
      int c = wave * 2 + j;
      async_copy16(xb + asrc[j] + k0, &As[c * 64 + lane]);
      async_copy16(wt + bsrc[j] + k0, &Bs[c * 64 + lane]);
    }
    __syncthreads();
#pragma unroll
    for (int ks = 0; ks < 2; ks++) {
      bf16x8 af[2], bfr[4];
#pragma unroll
      for (int mi = 0; mi < 2; mi++) af[mi] = *(const bf16x8*)&As[((wm * 2 + ks) * 2 + mi) * 64 + lane];
#pragma unroll
      for (int ni = 0; ni < 4; ni++) bfr[ni] = *(const bf16x8*)&Bs[((wn * 2 + ks) * 4 + ni) * 64 + lane];
#pragma unroll
      for (int mi = 0; mi < 2; mi++)
#pragma unroll
        for (int ni = 0; ni < 4; ni++)
          acc[mi][ni] = __builtin_amdgcn_mfma_f32_16x16x32_bf16(af[mi], bfr[ni], acc[mi][ni], 0, 0, 0);
    }
  }

  // store bf16 partials.  D: col=lane&15, row=(lane>>4)*4+reg
  unsigned short* p = pbuf + (long)kh * (8192L * 1024);
#pragma unroll
  for (int ni = 0; ni < 4; ni++) {
    int col = n0 + wn * 64 + ni * 16 + l15;
#pragma unroll
    for (int mi = 0; mi < 2; mi++) {
      int rbase = m0 + wm * 32 + mi * 16 + lq * 4;
#pragma unroll
      for (int r = 0; r < 4; r++) {
        p[(long)(rbase + r) * U0 + col] = f2bf(acc[mi][ni][r]);
      }
    }
  }
}

// ---------- kernel 5: reduce partials + bias + relu -> h bf16 (in place over pb0) ----------
// h aliases pb[0]: thread i reads its own 16B of pb0 and writes the same 16B.
__global__ __launch_bounds__(256) void reduce_kernel(unsigned short* __restrict__ pb,
                                                     const float* __restrict__ fc_b) {
  long i = ((long)blockIdx.x * 256 + threadIdx.x) * 8;
  const unsigned short* p1 = pb + 8192L * 1024;
  uint4 a = *(const uint4*)(pb + i);
  uint4 b = *(const uint4*)(p1 + i);
  int cb = (int)(i & (U0 - 1));
  float4 b0 = *(const float4*)(fc_b + cb);
  float4 b1 = *(const float4*)(fc_b + cb + 4);
  const unsigned int* aw = (const unsigned int*)&a;
  const unsigned int* bw = (const unsigned int*)&b;
  float bias[8] = {b0.x, b0.y, b0.z, b0.w, b1.x, b1.y, b1.z, b1.w};
  uint4 r;
  unsigned int* rw = (unsigned int*)&r;
#pragma unroll
  for (int j = 0; j < 4; j++) {
    union { unsigned int u; float f; } lo0, hi0, lo1, hi1;
    lo0.u = (aw[j] & 0xFFFFu) << 16; hi0.u = aw[j] & 0xFFFF0000u;
    lo1.u = (bw[j] & 0xFFFFu) << 16; hi1.u = bw[j] & 0xFFFF0000u;
    float vlo = lo0.f + lo1.f + bias[2 * j];
    float vhi = hi0.f + hi1.f + bias[2 * j + 1];
    vlo = vlo > 0.f ? vlo : 0.f;
    vhi = vhi > 0.f ? vhi : 0.f;
    rw[j] = pk2(vlo, vhi);
  }
  *(uint4*)(pb + i) = r;
}

// ---------- kernel 6: selected-head MLP + epilogue ----------
__global__ __launch_bounds__(256) void head_kernel(const unsigned short* __restrict__ h,
                                                   const unsigned short* __restrict__ w1t,
                                                   const float* __restrict__ W1,
                                                   const float* __restrict__ b1,
                                                   const float* __restrict__ W2,
                                                   const float* __restrict__ b2,
                                                   const float* __restrict__ ego,
                                                   const int* __restrict__ idxlist,
                                                   const int* __restrict__ meta,
                                                   float* __restrict__ out) {
  int hd = blockIdx.y;
  int off = meta[hd];
  int cnt = meta[hd + 1] - off;
  int t0 = blockIdx.x * 32;
  if (t0 >= cnt) return;

  __shared__ int ridx[32];
  __shared__ float h1s[32][257];
  __shared__ float w2s[1024];  // W2[hd] preloaded: [256][4]
  int tid = threadIdx.x;
  if (tid < 32) {
    int i = t0 + tid;
    ridx[tid] = idxlist[off + (i < cnt ? i : 0)];
  }
  *(float4*)&w2s[tid * 4] = *(const float4*)(W2 + (long)hd * 1024 + tid * 4);
  __syncthreads();

  int lane = tid & 63, wave = tid >> 6;
  int l15 = lane & 15, lq = lane >> 4;

  long abase[2];
#pragma unroll
  for (int mi = 0; mi < 2; mi++) abase[mi] = (long)ridx[mi * 16 + l15] * U0 + lq * 8;
  long bbase[4];
#pragma unroll
  for (int ni = 0; ni < 4; ni++)
    bbase[ni] = (long)(hd * 256 + wave * 64 + ni * 16 + l15) * 1024 + lq * 8;

  f32x4 zero = {0.f, 0.f, 0.f, 0.f};
  f32x4 acc[2][4];
#pragma unroll
  for (int mi = 0; mi < 2; mi++)
#pragma unroll
    for (int ni = 0; ni < 4; ni++) acc[mi][ni] = zero;

#pragma unroll 2
  for (int k0 = 0; k0 < 1024; k0 += 32) {
    bf16x8 af[2], bfr[4];
#pragma unroll
    for (int mi = 0; mi < 2; mi++) af[mi] = *(const bf16x8*)(h + abase[mi] + k0);
#pragma unroll
    for (int ni = 0; ni < 4; ni++) bfr[ni] = *(const bf16x8*)(w1t + bbase[ni] + k0);
#pragma unroll
    for (int mi = 0; mi < 2; mi++)
#pragma unroll
      for (int ni = 0; ni < 4; ni++)
        acc[mi][ni] = __builtin_amdgcn_mfma_f32_16x16x32_bf16(af[mi], bfr[ni], acc[mi][ni], 0, 0, 0);
  }

  // ego contribution (fp32 exact) + bias + relu -> LDS
  const float* W1e = W1 + (long)hd * 1027 * 256 + (long)1024 * 256;  // rows 1024..1026
#pragma unroll
  for (int mi = 0; mi < 2; mi++)
#pragma unroll
    for (int r = 0; r < 4; r++) {
      int rl = mi * 16 + lq * 4 + r;
      int b = ridx[rl];
      float e0 = ego[b * 3 + 0], e1 = ego[b * 3 + 1], e2 = ego[b * 3 + 2];
#pragma unroll
      for (int ni = 0; ni < 4; ni++) {
        int col = wave * 64 + ni * 16 + l15;
        float v = acc[mi][ni][r] + b1[hd * 256 + col]
                + e0 * W1e[col] + e1 * W1e[256 + col] + e2 * W1e[512 + col];
        h1s[rl][col] = v > 0.f ? v : 0.f;
      }
    }
  __syncthreads();

  // h2 = h1 @ W2[hd] + b2[hd]; tanh/softplus epilogue; scatter by original row
  if (tid < 128) {
    int t = tid >> 2, o2 = tid & 3;
    if (t0 + t < cnt) {
      float s0 = 0.f, s1 = 0.f, s2 = 0.f, s3 = 0.f;
#pragma unroll 4
      for (int i = 0; i < 256; i += 4) {
        s0 += h1s[t][i + 0] * w2s[(i + 0) * 4 + o2];
        s1 += h1s[t][i + 1] * w2s[(i + 1) * 4 + o2];
        s2 += h1s[t][i + 2] * w2s[(i + 2) * 4 + o2];
        s3 += h1s[t][i + 3] * w2s[(i + 3) * 4 + o2];
      }
      float sum = b2[hd * 4 + o2] + ((s0 + s1) + (s2 + s3));
      int b = ridx[t];
      float res;
      if (o2 < 2) {
        res = 5.0f * tanhf(sum * 0.2f);
      } else {
        float z = sum + 4.99323838f;  // log(exp(5)-1)
        res = (z > 20.f ? z : log1pf(expf(z))) + 1e-4f;
      }
      out[b * 4 + o2] = res;
    }
  }
}

// ---------- launcher ----------
extern "C" void kernel_launch(void* const* d_in, const int* in_sizes, int n_in,
                              void* d_out, int out_size, void* d_ws, size_t ws_size,
                              hipStream_t stream) {
  const float* x   = (const float*)d_in[0];
  const int*   cmd = (const int*)d_in[1];
  const float* ego = (const float*)d_in[2];
  const float* fcW = (const float*)d_in[3];
  const float* fcb = (const float*)d_in[4];
  const float* W1  = (const float*)d_in[5];
  const float* b1  = (const float*)d_in[6];
  const float* W2  = (const float*)d_in[7];
  const float* b2  = (const float*)d_in[8];
  float* out = (float*)d_out;

  char* ws = (char*)d_ws;
  unsigned short* xb   = (unsigned short*)(ws);                 // 128 MB  x bf16
  unsigned short* wt   = (unsigned short*)(ws + 134217728);     // 16 MB   fc_W^T bf16
  unsigned short* pbuf = (unsigned short*)(ws + 150994944);     // 32 MB   partials [2][8192][1024]; pb0 becomes h
  unsigned short* hbuf = pbuf;                                  // h aliases pb0 (reduce is in-place)
  unsigned short* w1t  = (unsigned short*)(ws + 184549376);     // 3 MB    W1^T bf16
  int* idxlist         = (int*)(ws + 187695104);                // 32 KB
  int* meta            = (int*)(ws + 187727872);                // 7 ints

  hipLaunchKernelGGL(cvt_x_kernel, dim3(2048), dim3(256), 0, stream, x, xb);
  hipLaunchKernelGGL(transpose_cvt_kernel, dim3(128, 16, 1), dim3(256), 0, stream,
                     fcW, wt, 8192, 1024, 0L, 0L);
  hipLaunchKernelGGL(transpose_cvt_kernel, dim3(16, 4, 6), dim3(256), 0, stream,
                     W1, w1t, 1024, 256, (long)1027 * 256, (long)256 * 1024);
  hipLaunchKernelGGL(bucket_kernel, dim3(1), dim3(1024), 0, stream, cmd, idxlist, meta);
  hipLaunchKernelGGL(gemm_kernel, dim3(1024), dim3(512), 0, stream, xb, wt, pbuf);
  hipLaunchKernelGGL(reduce_kernel, dim3(4096), dim3(256), 0, stream, pbuf, fcb);
  hipLaunchKernelGGL(head_kernel, dim3(256, 6), dim3(256), 0, stream,
                     hbuf, w1t, W1, b1, W2, b2, ego, idxlist, meta, out);
}

// Round 19
// 761.464 us; speedup vs baseline: 1.0885x; 1.0211x over previous
//
#include <hip/hip_runtime.h>
#include <stdint.h>

typedef short bf16x8 __attribute__((ext_vector_type(8)));
typedef float f32x4 __attribute__((ext_vector_type(4)));

#define BATCH 8192
#define EMBED 8192
#define U0    1024
#define U1    256
#define NHEAD 6

// ---------- helpers ----------
__device__ __forceinline__ unsigned short f2bf(float f) {
  union { float f; unsigned int u; } v; v.f = f;
  unsigned int u = v.u;
  unsigned int r = u + 0x7FFFu + ((u >> 16) & 1u);  // RNE
  return (unsigned short)(r >> 16);
}
__device__ __forceinline__ unsigned int pk2(float lo, float hi) {
  return (unsigned int)f2bf(lo) | ((unsigned int)f2bf(hi) << 16);
}
__device__ __forceinline__ void async_copy16(const void* g, void* l) {
  __builtin_amdgcn_global_load_lds((const __attribute__((address_space(1))) void*)g,
                                   (__attribute__((address_space(3))) void*)l, 16, 0, 0);
}

// ---------- kernel 1: x fp32 -> bf16 (grid-stride, 2048 blocks per G11) ----------
__global__ void cvt_x_kernel(const float* __restrict__ x, unsigned short* __restrict__ xb) {
  const long total = (long)BATCH * EMBED;
  const long stride = (long)gridDim.x * blockDim.x * 8;
  for (long i = ((long)blockIdx.x * blockDim.x + threadIdx.x) * 8; i < total; i += stride) {
    float4 a = *(const float4*)(x + i);
    float4 b = *(const float4*)(x + i + 4);
    uint4 r;
    r.x = pk2(a.x, a.y); r.y = pk2(a.z, a.w);
    r.z = pk2(b.x, b.y); r.w = pk2(b.z, b.w);
    *(uint4*)(xb + i) = r;
  }
}

// ---------- kernel 2: transpose + convert: in[R][C] fp32 -> out[C][R] bf16 ----------
__global__ void transpose_cvt_kernel(const float* __restrict__ in, unsigned short* __restrict__ out,
                                     int R, int C, long in_z, long out_z) {
  __shared__ unsigned short tile[64][65];
  const float* inp = in + (long)blockIdx.z * in_z;
  unsigned short* outp = out + (long)blockIdx.z * out_z;
  int r0 = blockIdx.x * 64;
  int c0 = blockIdx.y * 64;
  int lc = threadIdx.x & 63;
  int lr = threadIdx.x >> 6;  // 0..3
#pragma unroll
  for (int i = 0; i < 16; i++) {
    int r = lr + i * 4;
    tile[r][lc] = f2bf(inp[(long)(r0 + r) * C + (c0 + lc)]);
  }
  __syncthreads();
#pragma unroll
  for (int i = 0; i < 16; i++) {
    int c = lr + i * 4;
    outp[(long)(c0 + c) * R + (r0 + lc)] = tile[lc][c];
  }
}

// ---------- kernel 3: bucket rows by command (single block, ballot-aggregated) ----------
__global__ void bucket_kernel(const int* __restrict__ cmd, int* __restrict__ idxlist,
                              int* __restrict__ meta) {
  __shared__ int cnt[NHEAD], cur[NHEAD], off[NHEAD + 1];
  int tid = threadIdx.x;            // 1024 threads = 16 waves
  int lane = tid & 63, wave = tid >> 6;
  if (tid < NHEAD) cnt[tid] = 0;
  __syncthreads();
  for (int base = wave * 64; base < BATCH; base += 1024) {
    int c = cmd[base + lane];
#pragma unroll
    for (int h2 = 0; h2 < NHEAD; h2++) {
      unsigned long long m = __ballot(c == h2);
      if (lane == 0 && m) atomicAdd(&cnt[h2], __popcll(m));
    }
  }
  __syncthreads();
  if (tid == 0) {
    int s = 0;
    for (int h2 = 0; h2 < NHEAD; h2++) { off[h2] = s; s += cnt[h2]; }
    off[NHEAD] = s;
  }
  __syncthreads();
  if (tid < NHEAD) cur[tid] = off[tid];
  if (tid <= NHEAD) meta[tid] = off[tid];
  __syncthreads();
  for (int base = wave * 64; base < BATCH; base += 1024) {
    int b = base + lane;
    int c = cmd[b];
    int pos = 0;
#pragma unroll
    for (int h2 = 0; h2 < NHEAD; h2++) {
      unsigned long long m = __ballot(c == h2);
      if (m) {
        int leader = (int)(__ffsll((unsigned long long)m) - 1);
        int wbase = 0;
        if (lane == leader) wbase = atomicAdd(&cur[h2], __popcll(m));
        wbase = __shfl(wbase, leader);
        if (c == h2) pos = wbase + __popcll(m & ((1ULL << lane) - 1ULL));
      }
    }
    idxlist[pos] = b;
  }
}

// ---------- kernel 4: GEMM  h = relu(xb @ fc_W + fc_b), 2-phase double-buffered ----------
// A = xb[8192][8192] bf16; B = wt[1024][8192] bf16 (fc_W^T).
// 128x128 tile, BK=64, 8 waves (512 thr) 4x2, wave-tile 32x64 (2x4 of 16x16x32).
// T3 minimum-2-phase: stage tile t+1 into buf^1 BEFORE computing tile t; single
// __syncthreads() (= vmcnt(0)+barrier) per k-step. Load latency overlaps compute.
// LDS 64 KB/block -> 2 blocks/CU (the measured residency cap anyway, R2/R3/R8/R9).
// Single-K (split-K measured neutral, R3 vs R9); grid 512 = 8 xcd x 8 by x 8 bx,
// bijective XCD swizzle, bx fastest (R3-measured FETCH 131 MB = minimal).
__global__ __launch_bounds__(512) void gemm_kernel(const unsigned short* __restrict__ xb,
                                                   const unsigned short* __restrict__ wt,
                                                   const float* __restrict__ fc_b,
                                                   unsigned short* __restrict__ h) {
  __shared__ uint4 As[2][1024];  // 2 x 16 KB: slot ((wm*2+ks)*2+mi)*64 + lane
  __shared__ uint4 Bs[2][1024];  // 2 x 16 KB: slot ((wn*2+ks)*4+ni)*64 + lane
  int tid  = threadIdx.x;
  int lane = tid & 63;
  int wave = tid >> 6;        // 0..7
  int wm = wave >> 1;         // 0..3
  int wn = wave & 1;          // 0..1

  int f = blockIdx.x;         // 0..511
  int xcd = f & 7;
  int idx = f >> 3;           // 0..63
  int by = xcd * 8 + (idx >> 3);
  int bx = idx & 7;
  int m0 = by * 128;
  int n0 = bx * 128;
  int l15 = lane & 15, lq = lane >> 4;

  // staging: 2048 slots over 512 lanes = 2 A-copies + 2 B-copies per lane.
  long asrc[2], bsrc[2];
  int aslot[2], bslot[2];
#pragma unroll
  for (int j = 0; j < 2; j++) {
    int ca = wave * 2 + j;                 // 0..15 = (cwm*2+cks)*2+cmi
    int cwm = ca >> 2, cka = (ca >> 1) & 1, cmi = ca & 1;
    asrc[j] = (long)(m0 + cwm * 32 + cmi * 16 + l15) * EMBED + cka * 32 + lq * 8;
    aslot[j] = ca * 64 + lane;
    int cb = wave * 2 + j;                 // 0..15 = (cwn*2+cks)*4+cni
    int cwn = cb >> 3, ckb = (cb >> 2) & 1, cni = cb & 3;
    bsrc[j] = (long)(n0 + cwn * 64 + cni * 16 + l15) * EMBED + ckb * 32 + lq * 8;
    bslot[j] = cb * 64 + lane;
  }

  f32x4 zero = {0.f, 0.f, 0.f, 0.f};
  f32x4 acc[2][4];
#pragma unroll
  for (int mi = 0; mi < 2; mi++)
#pragma unroll
    for (int ni = 0; ni < 4; ni++) acc[mi][ni] = zero;

  // prologue: stage tile 0 into buf 0
#pragma unroll
  for (int j = 0; j < 2; j++) {
    async_copy16(xb + asrc[j], &As[0][aslot[j]]);
    async_copy16(wt + bsrc[j], &Bs[0][bslot[j]]);
  }
  __syncthreads();

  int cur = 0;
  for (int t = 0; t < 128; ++t) {
    // stage tile t+1 into the other buffer BEFORE computing tile t
    if (t < 127) {
      long kn = (long)(t + 1) * 64;
#pragma unroll
      for (int j = 0; j < 2; j++) {
        async_copy16(xb + asrc[j] + kn, &As[cur ^ 1][aslot[j]]);
        async_copy16(wt + bsrc[j] + kn, &Bs[cur ^ 1][bslot[j]]);
      }
    }
    // compute tile t from buf[cur]
#pragma unroll
    for (int ks = 0; ks < 2; ks++) {
      bf16x8 af[2], bfr[4];
#pragma unroll
      for (int mi = 0; mi < 2; mi++) af[mi] = *(const bf16x8*)&As[cur][((wm * 2 + ks) * 2 + mi) * 64 + lane];
#pragma unroll
      for (int ni = 0; ni < 4; ni++) bfr[ni] = *(const bf16x8*)&Bs[cur][((wn * 2 + ks) * 4 + ni) * 64 + lane];
#pragma unroll
      for (int mi = 0; mi < 2; mi++)
#pragma unroll
        for (int ni = 0; ni < 4; ni++)
          acc[mi][ni] = __builtin_amdgcn_mfma_f32_16x16x32_bf16(af[mi], bfr[ni], acc[mi][ni], 0, 0, 0);
    }
    // one barrier per k-step: compiler emits s_waitcnt vmcnt(0) lgkmcnt(0) before
    // s_barrier -> drains the t+1 stage (residual latency only) + protects buf reuse.
    __syncthreads();
    cur ^= 1;
  }

  // epilogue: +bias, relu, store bf16.  D: col=lane&15, row=(lane>>4)*4+reg
#pragma unroll
  for (int ni = 0; ni < 4; ni++) {
    int col = n0 + wn * 64 + ni * 16 + l15;
    float bias = fc_b[col];
#pragma unroll
    for (int mi = 0; mi < 2; mi++) {
      int rbase = m0 + wm * 32 + mi * 16 + lq * 4;
#pragma unroll
      for (int r = 0; r < 4; r++) {
        float v = acc[mi][ni][r] + bias;
        v = v > 0.f ? v : 0.f;
        h[(long)(rbase + r) * U0 + col] = f2bf(v);
      }
    }
  }
}

// ---------- kernel 5: selected-head MLP + epilogue ----------
__global__ __launch_bounds__(256) void head_kernel(const unsigned short* __restrict__ h,
                                                   const unsigned short* __restrict__ w1t,
                                                   const float* __restrict__ W1,
                                                   const float* __restrict__ b1,
                                                   const float* __restrict__ W2,
                                                   const float* __restrict__ b2,
                                                   const float* __restrict__ ego,
                                                   const int* __restrict__ idxlist,
                                                   const int* __restrict__ meta,
                                                   float* __restrict__ out) {
  int hd = blockIdx.y;
  int off = meta[hd];
  int cnt = meta[hd + 1] - off;
  int t0 = blockIdx.x * 32;
  if (t0 >= cnt) return;

  __shared__ int ridx[32];
  __shared__ float h1s[32][257];
  __shared__ float w2s[1024];  // W2[hd] preloaded: [256][4]
  int tid = threadIdx.x;
  if (tid < 32) {
    int i = t0 + tid;
    ridx[tid] = idxlist[off + (i < cnt ? i : 0)];
  }
  *(float4*)&w2s[tid * 4] = *(const float4*)(W2 + (long)hd * 1024 + tid * 4);
  __syncthreads();

  int lane = tid & 63, wave = tid >> 6;
  int l15 = lane & 15, lq = lane >> 4;

  long abase[2];
#pragma unroll
  for (int mi = 0; mi < 2; mi++) abase[mi] = (long)ridx[mi * 16 + l15] * U0 + lq * 8;
  long bbase[4];
#pragma unroll
  for (int ni = 0; ni < 4; ni++)
    bbase[ni] = (long)(hd * 256 + wave * 64 + ni * 16 + l15) * 1024 + lq * 8;

  f32x4 zero = {0.f, 0.f, 0.f, 0.f};
  f32x4 acc[2][4];
#pragma unroll
  for (int mi = 0; mi < 2; mi++)
#pragma unroll
    for (int ni = 0; ni < 4; ni++) acc[mi][ni] = zero;

#pragma unroll 2
  for (int k0 = 0; k0 < 1024; k0 += 32) {
    bf16x8 af[2], bfr[4];
#pragma unroll
    for (int mi = 0; mi < 2; mi++) af[mi] = *(const bf16x8*)(h + abase[mi] + k0);
#pragma unroll
    for (int ni = 0; ni < 4; ni++) bfr[ni] = *(const bf16x8*)(w1t + bbase[ni] + k0);
#pragma unroll
    for (int mi = 0; mi < 2; mi++)
#pragma unroll
      for (int ni = 0; ni < 4; ni++)
        acc[mi][ni] = __builtin_amdgcn_mfma_f32_16x16x32_bf16(af[mi], bfr[ni], acc[mi][ni], 0, 0, 0);
  }

  // ego contribution (fp32 exact) + bias + relu -> LDS
  const float* W1e = W1 + (long)hd * 1027 * 256 + (long)1024 * 256;  // rows 1024..1026
#pragma unroll
  for (int mi = 0; mi < 2; mi++)
#pragma unroll
    for (int r = 0; r < 4; r++) {
      int rl = mi * 16 + lq * 4 + r;
      int b = ridx[rl];
      float e0 = ego[b * 3 + 0], e1 = ego[b * 3 + 1], e2 = ego[b * 3 + 2];
#pragma unroll
      for (int ni = 0; ni < 4; ni++) {
        int col = wave * 64 + ni * 16 + l15;
        float v = acc[mi][ni][r] + b1[hd * 256 + col]
                + e0 * W1e[col] + e1 * W1e[256 + col] + e2 * W1e[512 + col];
        h1s[rl][col] = v > 0.f ? v : 0.f;
      }
    }
  __syncthreads();

  // h2 = h1 @ W2[hd] + b2[hd]; tanh/softplus epilogue; scatter by original row
  if (tid < 128) {
    int t = tid >> 2, o2 = tid & 3;
    if (t0 + t < cnt) {
      float s0 = 0.f, s1 = 0.f, s2 = 0.f, s3 = 0.f;
#pragma unroll 4
      for (int i = 0; i < 256; i += 4) {
        s0 += h1s[t][i + 0] * w2s[(i + 0) * 4 + o2];
        s1 += h1s[t][i + 1] * w2s[(i + 1) * 4 + o2];
        s2 += h1s[t][i + 2] * w2s[(i + 2) * 4 + o2];
        s3 += h1s[t][i + 3] * w2s[(i + 3) * 4 + o2];
      }
      float sum = b2[hd * 4 + o2] + ((s0 + s1) + (s2 + s3));
      int b = ridx[t];
      float res;
      if (o2 < 2) {
        res = 5.0f * tanhf(sum * 0.2f);
      } else {
        float z = sum + 4.99323838f;  // log(exp(5)-1)
        res = (z > 20.f ? z : log1pf(expf(z))) + 1e-4f;
      }
      out[b * 4 + o2] = res;
    }
  }
}

// ---------- launcher ----------
extern "C" void kernel_launch(void* const* d_in, const int* in_sizes, int n_in,
                              void* d_out, int out_size, void* d_ws, size_t ws_size,
                              hipStream_t stream) {
  const float* x   = (const float*)d_in[0];
  const int*   cmd = (const int*)d_in[1];
  const float* ego = (const float*)d_in[2];
  const float* fcW = (const float*)d_in[3];
  const float* fcb = (const float*)d_in[4];
  const float* W1  = (const float*)d_in[5];
  const float* b1  = (const float*)d_in[6];
  const float* W2  = (const float*)d_in[7];
  const float* b2  = (const float*)d_in[8];
  float* out = (float*)d_out;

  char* ws = (char*)d_ws;
  unsigned short* xb   = (unsigned short*)(ws);                 // 128 MB  x bf16
  unsigned short* wt   = (unsigned short*)(ws + 134217728);     // 16 MB   fc_W^T bf16
  unsigned short* hbuf = (unsigned short*)(ws + 150994944);     // 16 MB   h bf16
  unsigned short* w1t  = (unsigned short*)(ws + 167772160);     // 3 MB    W1^T bf16
  int* idxlist         = (int*)(ws + 170917888);                // 32 KB
  int* meta            = (int*)(ws + 170950656);                // 7 ints

  hipLaunchKernelGGL(cvt_x_kernel, dim3(2048), dim3(256), 0, stream, x, xb);
  hipLaunchKernelGGL(transpose_cvt_kernel, dim3(128, 16, 1), dim3(256), 0, stream,
                     fcW, wt, 8192, 1024, 0L, 0L);
  hipLaunchKernelGGL(transpose_cvt_kernel, dim3(16, 4, 6), dim3(256), 0, stream,
                     W1, w1t, 1024, 256, (long)1027 * 256, (long)256 * 1024);
  hipLaunchKernelGGL(bucket_kernel, dim3(1), dim3(1024), 0, stream, cmd, idxlist, meta);
  hipLaunchKernelGGL(gemm_kernel, dim3(512), dim3(512), 0, stream, xb, wt, fcb, hbuf);
  hipLaunchKernelGGL(head_kernel, dim3(256, 6), dim3(256), 0, stream,
                     hbuf, w1t, W1, b1, W2, b2, ego, idxlist, meta, out);
}